// Round 4
// baseline (12854.854 us; speedup 1.0000x reference)
//
#include <hip/hip_runtime.h>
#include <hip/hip_fp16.h>
#include <cstdint>
#include <cstddef>

#define B_   2048
#define T_   13
#define D0_  188
#define H_   256
#define G_   768   // 3*H
#define L_   8
#define DC_  512   // 2*H concat width

__device__ __forceinline__ float sigmoidf_(float x){ return 1.f/(1.f + expf(-x)); }

__device__ __forceinline__ float ldf_(const float* p){ return *p; }
__device__ __forceinline__ float ldf_(const __half* p){ return __half2float(*p); }

// ---------------- fallback: zero d_out (diagnostic path if ws_size is tiny) ----------------
__global__ __launch_bounds__(256) void k_zero(float* __restrict__ o, int n){
  int i = blockIdx.x*256 + threadIdx.x;
  if (i < n) o[i] = 0.f;
}

// ---------------- transpose W_hh: [16][G][H] fp32 -> WT [16][H][G] fp16 ----------------
__global__ __launch_bounds__(256) void k_transpose_whh(const float* __restrict__ W,
                                                       __half* __restrict__ WT){
  __shared__ float tile[32][33];
  int ld = blockIdx.z;
  int g0 = blockIdx.x*32, k0 = blockIdx.y*32;
  int tx = threadIdx.x & 31, ty = threadIdx.x >> 5; // 32 x 8
  const float* Wl  = W  + (size_t)ld*G_*H_;
  __half*      WTl = WT + (size_t)ld*H_*G_;
#pragma unroll
  for (int i=0;i<4;i++)
    tile[ty + 8*i][tx] = Wl[(size_t)(g0 + ty + 8*i)*H_ + k0 + tx];
  __syncthreads();
#pragma unroll
  for (int i=0;i<4;i++)
    WTl[(size_t)(k0 + ty + 8*i)*G_ + g0 + tx] = __float2half(tile[tx][ty + 8*i]);
}

// ---------------- gx GEMM over one batch-chunk of C rows (local row ids 0..C-1):
// gx[dir][t][b][g] = b_ih[dir][g] + sum_k inp[b][t][k] * Wi[dir][g][k]
// 128(b) x 64(g) tile, 256 threads, 8x4 acc/thread, K-chunks of 16 staged in LDS (fp32 compute).
template<typename TIN>
__global__ __launch_bounds__(256) void k_gx_gemm(
    const TIN* __restrict__ inp, int Kin,      // [C][T][Kin]
    const float* __restrict__ Wi,              // [2][G][Kin] fp32
    const float* __restrict__ bihL,            // [2][G] fp32
    __half* __restrict__ gx, int C)            // [2][T][C][G] fp16
{
  __shared__ __align__(16) float As[128][20];
  __shared__ __align__(16) float Bs[64][20];
  int bz = blockIdx.z; int dir = bz / T_; int t = bz % T_;
  int b0 = blockIdx.x * 128, g0 = blockIdx.y * 64;
  int tid = threadIdx.x, tx = tid & 15, ty = tid >> 4;
  float acc[8][4];
#pragma unroll
  for (int i=0;i<8;i++)
#pragma unroll
    for (int j=0;j<4;j++) acc[i][j]=0.f;
  const int lc = tid & 15;       // k within chunk (for loads)
  const int lr = tid >> 4;       // row base (for loads)
  for (int k0=0;k0<Kin;k0+=16){
#pragma unroll
    for (int i=0;i<8;i++){
      int r = lr + 16*i; int gk = k0 + lc;
      As[r][lc] = (gk < Kin) ? ldf_(&inp[((size_t)(b0 + r)*T_ + t)*Kin + gk]) : 0.f;
    }
#pragma unroll
    for (int i=0;i<4;i++){
      int r = lr + 16*i; int gk = k0 + lc;
      Bs[r][lc] = (gk < Kin) ? Wi[((size_t)dir*G_ + g0 + r)*Kin + gk] : 0.f;
    }
    __syncthreads();
#pragma unroll
    for (int kq=0;kq<4;kq++){
      float4 a4[8], b4[4];
#pragma unroll
      for (int i=0;i<8;i++) a4[i] = *(const float4*)&As[ty + 16*i][kq*4];
#pragma unroll
      for (int j=0;j<4;j++) b4[j] = *(const float4*)&Bs[tx + 16*j][kq*4];
#pragma unroll
      for (int i=0;i<8;i++)
#pragma unroll
        for (int j=0;j<4;j++){
          acc[i][j] += a4[i].x*b4[j].x + a4[i].y*b4[j].y
                     + a4[i].z*b4[j].z + a4[i].w*b4[j].w;
        }
    }
    __syncthreads();
  }
  size_t base = (size_t)(dir*T_ + t)*C*G_;
#pragma unroll
  for (int i=0;i<8;i++){
    int b = b0 + ty + 16*i;
#pragma unroll
    for (int j=0;j<4;j++){
      int g = g0 + tx + 16*j;
      gx[base + (size_t)b*G_ + g] = __float2half(acc[i][j] + bihL[dir*G_ + g]);
    }
  }
}

// ---------------- GRU recurrence over one chunk: one block = 16 rows x 1 direction, all T steps.
// h in LDS (fp32); thread j owns gate columns {j, 256+j, 512+j}; W_hh pre-transposed k-major fp16.
__global__ __launch_bounds__(256) void k_gru_rec(
    const __half* __restrict__ gx,    // [2][T][C][G] fp16 (this layer, this chunk)
    const __half* __restrict__ WTl,   // [2][H][G] fp16 (this layer, k-major)
    const float*  __restrict__ bhhL,  // [2][G] fp32
    __half* __restrict__ out,         // [C][T][DC] fp16; dir writes cols dir*H..dir*H+255
    float*  __restrict__ hsum,        // [2][C][H] fp32 running sum of h_finals
    int init, int C)
{
  int dir = blockIdx.y;
  int b0  = blockIdx.x * 16;
  int j   = threadIdx.x;           // 0..255 gate column
  __shared__ float hs[16][H_];
#pragma unroll
  for (int b=0;b<16;b++) hs[b][j] = 0.f;
  __syncthreads();
  const float bR = bhhL[dir*G_ + j];
  const float bZ = bhhL[dir*G_ + H_ + j];
  const float bN = bhhL[dir*G_ + 2*H_ + j];
  const __half* WTd = WTl + (size_t)dir*H_*G_;
  for (int t=0;t<T_;t++){
    int tt = dir ? (T_-1-t) : t;
    float aR[16], aZ[16], aN[16];
#pragma unroll
    for (int b=0;b<16;b++){ aR[b]=bR; aZ[b]=bZ; aN[b]=bN; }
    for (int k=0;k<H_;k+=4){
      float4 h4[16];
#pragma unroll
      for (int b=0;b<16;b++) h4[b] = *(const float4*)&hs[b][k];
#pragma unroll
      for (int kk=0;kk<4;kk++){
        const __half* wrow = WTd + (size_t)(k+kk)*G_;
        float w0 = __half2float(wrow[j]);
        float w1 = __half2float(wrow[H_ + j]);
        float w2 = __half2float(wrow[2*H_ + j]);
#pragma unroll
        for (int b=0;b<16;b++){
          float hv = ((const float*)&h4[b])[kk];
          aR[b] = fmaf(hv, w0, aR[b]);
          aZ[b] = fmaf(hv, w1, aZ[b]);
          aN[b] = fmaf(hv, w2, aN[b]);
        }
      }
    }
    __syncthreads();   // all hs reads for this step complete
    const __half* gxp = gx + ((size_t)(dir*T_ + tt)*C + b0)*G_;
#pragma unroll
    for (int b=0;b<16;b++){
      float gr = __half2float(gxp[(size_t)b*G_ + j]);
      float gz = __half2float(gxp[(size_t)b*G_ + H_  + j]);
      float gn = __half2float(gxp[(size_t)b*G_ + 2*H_ + j]);
      float r = sigmoidf_(gr + aR[b]);
      float z = sigmoidf_(gz + aZ[b]);
      float n = tanhf(gn + r*aN[b]);   // b_hn folded into aN -> multiplied by r (PyTorch semantics)
      float hnew = (1.f - z)*n + z*hs[b][j];
      out[((size_t)(b0+b)*T_ + tt)*DC_ + dir*H_ + j] = __float2half(hnew);
      hs[b][j] = hnew;
    }
    __syncthreads();   // hs update visible before next step's reads
  }
  if (init){
#pragma unroll
    for (int b=0;b<16;b++)
      hsum[((size_t)dir*C + b0 + b)*H_ + j] = hs[b][j];
  } else {
#pragma unroll
    for (int b=0;b<16;b++)
      hsum[((size_t)dir*C + b0 + b)*H_ + j] += hs[b][j];
  }
}

// ---------------- head (per chunk): mean of 16 h_finals -> 256->64 silu -> 64->32 silu -> 32->1
__global__ __launch_bounds__(256) void k_head(
    const float* __restrict__ hsum, // [2][C][H] (sum over 8 layers per dir)
    const float* __restrict__ W1, const float* __restrict__ b1,
    const float* __restrict__ W2, const float* __restrict__ b2,
    const float* __restrict__ Wc, const float* __restrict__ bc,
    float* __restrict__ outp, int C) // outp pre-offset to chunk base
{
  __shared__ float hb[4][H_];
  __shared__ float y1[4][64];
  __shared__ float y2[4][32];
  int w = threadIdx.x >> 6, lane = threadIdx.x & 63;
  int b = blockIdx.x*4 + w;
  for (int i=lane;i<H_;i+=64){
    float s = hsum[(size_t)b*H_ + i] + hsum[((size_t)C + b)*H_ + i];
    hb[w][i] = s * (1.f/16.f);
  }
  __syncthreads();
  {
    float s = b1[lane];
#pragma unroll 8
    for (int k=0;k<H_;k++) s = fmaf(W1[lane*H_ + k], hb[w][k], s);
    y1[w][lane] = s * (1.f/(1.f+expf(-s)));
  }
  __syncthreads();
  if (lane < 32){
    float s = b2[lane];
#pragma unroll
    for (int k=0;k<64;k++) s = fmaf(W2[lane*64 + k], y1[w][k], s);
    y2[w][lane] = s * (1.f/(1.f+expf(-s)));
  }
  __syncthreads();
  if (lane == 0){
    float s = bc[0];
#pragma unroll
    for (int k=0;k<32;k++) s = fmaf(Wc[k], y2[w][k], s);
    outp[b] = s;
  }
}

static inline size_t al256(size_t x){ return (x + 255) & ~(size_t)255; }

extern "C" void kernel_launch(void* const* d_in, const int* in_sizes, int n_in,
                              void* d_out, int out_size, void* d_ws, size_t ws_size,
                              hipStream_t stream)
{
  const float* x    = (const float*)d_in[0];
  const float* Wih0 = (const float*)d_in[1];
  const float* WihR = (const float*)d_in[2];
  const float* Whh  = (const float*)d_in[3];
  const float* bih  = (const float*)d_in[4];
  const float* bhh  = (const float*)d_in[5];
  const float* W1p  = (const float*)d_in[6];
  const float* b1p  = (const float*)d_in[7];
  const float* W2p  = (const float*)d_in[8];
  const float* b2p  = (const float*)d_in[9];
  const float* Wcp  = (const float*)d_in[10];
  const float* bcp  = (const float*)d_in[11];
  float* outp = (float*)d_out;
  (void)in_sizes; (void)n_in;

  // ---- pick smallest chunk count NC whose ws footprint fits ws_size ----
  // footprint(C): gx fp16 [2][T][C][G] + buf fp16 [C][T][DC] + WT fp16 [16][H][G] + hsum fp32 [2][C][H]
  auto need = [](int nc) -> size_t {
    size_t c = B_ / nc;
    size_t s = 0;
    s += al256((size_t)2*T_*c*G_*sizeof(__half));
    s += al256((size_t)c*T_*DC_*sizeof(__half));
    s += al256((size_t)16*H_*G_*sizeof(__half));
    s += al256((size_t)2*c*H_*sizeof(float));
    return s;
  };
  const int ncs[5] = {1,2,4,8,16};
  int NC = 16; bool fits = false;
  for (int i=0;i<5;i++){ if (need(ncs[i]) <= ws_size){ NC = ncs[i]; fits = true; break; } }

  if (!fits){
    // ws too small even for NC=16 (13.5 MB): emit zeros -> clean absmax-failure diagnostic,
    // never touch d_ws.
    k_zero<<<(out_size + 255)/256, 256, 0, stream>>>(outp, out_size);
    return;
  }

  const size_t C = B_ / NC;
  char* p = (char*)d_ws;
  __half* gx   = (__half*)p;  p += al256((size_t)2*T_*C*G_*sizeof(__half));
  __half* buf  = (__half*)p;  p += al256((size_t)C*T_*DC_*sizeof(__half));
  __half* WT   = (__half*)p;  p += al256((size_t)16*H_*G_*sizeof(__half));
  float*  hsum = (float*)p;   p += al256((size_t)2*C*H_*sizeof(float));

  k_transpose_whh<<<dim3(G_/32, H_/32, 16), 256, 0, stream>>>(Whh, WT);

  for (int cc=0; cc<NC; cc++){
    const size_t b0c = (size_t)cc * C;
    for (int l=0;l<L_;l++){
      int Kin         = (l==0) ? D0_ : DC_;
      const float* Wi = (l==0) ? Wih0 : (WihR + (size_t)(l-1)*2*G_*DC_);
      if (l==0){
        k_gx_gemm<float><<<dim3(C/128, G_/64, 2*T_), 256, 0, stream>>>(
            x + b0c*T_*D0_, Kin, Wi, bih + (size_t)l*2*G_, gx, (int)C);
      } else {
        k_gx_gemm<__half><<<dim3(C/128, G_/64, 2*T_), 256, 0, stream>>>(
            buf, Kin, Wi, bih + (size_t)l*2*G_, gx, (int)C);
      }
      // both GEMM dispatches above finish reading `buf` before rec overwrites it (stream order)
      k_gru_rec<<<dim3(C/16, 2), 256, 0, stream>>>(
          gx, WT + (size_t)l*2*H_*G_, bhh + (size_t)l*2*G_, buf,
          hsum, (l==0) ? 1 : 0, (int)C);
    }
    k_head<<<dim3(C/4), 256, 0, stream>>>(hsum, W1p,b1p,W2p,b2p,Wcp,bcp,
                                          outp + b0c, (int)C);
  }
}

// Round 6
// 3900.871 us; speedup vs baseline: 3.2954x; 3.2954x over previous
//
#include <hip/hip_runtime.h>
#include <hip/hip_fp16.h>
#include <cstdint>
#include <cstddef>

#define B_   2048
#define T_   13
#define D0_  188
#define H_   256
#define G_   768   // 3*H
#define L_   8
#define DC_  512   // 2*H concat width

typedef _Float16 half8_ __attribute__((ext_vector_type(8)));
typedef float    f32x4_ __attribute__((ext_vector_type(4)));

__device__ __forceinline__ float sigmoidf_(float x){ return 1.f/(1.f + expf(-x)); }

// ---------------- fallback: zero d_out (diagnostic path if ws_size is tiny) ----------------
__global__ __launch_bounds__(256) void k_zero(float* __restrict__ o, int n){
  int i = blockIdx.x*256 + threadIdx.x;
  if (i < n) o[i] = 0.f;
}

// ---------------- transpose W_hh: [16][G][H] fp32 -> WT [16][H][G] fp16 ----------------
__global__ __launch_bounds__(256) void k_transpose_whh(const float* __restrict__ W,
                                                       __half* __restrict__ WT){
  __shared__ float tile[32][33];
  int ld = blockIdx.z;
  int g0 = blockIdx.x*32, k0 = blockIdx.y*32;
  int tx = threadIdx.x & 31, ty = threadIdx.x >> 5; // 32 x 8
  const float* Wl  = W  + (size_t)ld*G_*H_;
  __half*      WTl = WT + (size_t)ld*H_*G_;
#pragma unroll
  for (int i=0;i<4;i++)
    tile[ty + 8*i][tx] = Wl[(size_t)(g0 + ty + 8*i)*H_ + k0 + tx];
  __syncthreads();
#pragma unroll
  for (int i=0;i<4;i++)
    WTl[(size_t)(k0 + ty + 8*i)*G_ + g0 + tx] = __float2half(tile[tx][ty + 8*i]);
}

// ---------------- staging helpers: load 8 elems (guarded) -> 8 halfs ----------------
__device__ __forceinline__ void load8_(const float* s, int rem, __half* d){
  if (rem >= 8){
#pragma unroll
    for (int u=0;u<8;u++) d[u] = __float2half(s[u]);
  } else {
#pragma unroll
    for (int u=0;u<8;u++) d[u] = (u<rem) ? __float2half(s[u]) : __ushort_as_half((unsigned short)0);
  }
}
__device__ __forceinline__ void load8_(const __half* s, int rem, __half* d){
  if (rem >= 8){
    *(uint4*)d = *(const uint4*)s;      // 16B vector load (layers>=1: always aligned, K%8==0)
  } else {
#pragma unroll
    for (int u=0;u<8;u++) d[u] = (u<rem) ? s[u] : __ushort_as_half((unsigned short)0);
  }
}

// ---------------- gx GEMM via MFMA f16:
// gx[dir][t][b][g] = b_ih[dir][g] + sum_k inp[b][t][k] * Wi[dir][g][k]
// BM=128 x BN=64 x BK=32, 256 threads (4 waves); wave owns 32 rows x 64 cols = 2x4 16x16 tiles.
// Fragment layouts (m89/m91-verified): A/B lane: row=lane&15, k=(lane>>4)*8+j; D: col=lane&15, row=quad*4+reg.
template<typename TIN>
__global__ __launch_bounds__(256) void k_gx_mfma(
    const TIN* __restrict__ inp,     // [C][T][Kmem]  (fp32 for layer 0, fp16 after)
    const float* __restrict__ Wi,    // [2][G][Kmem] fp32
    const float* __restrict__ bihL,  // [2][G] fp32
    __half* __restrict__ gx,         // [2][T][C][G] fp16
    int C, int Kmem, int Kpad)
{
  __shared__ __half As[128][40];     // stride 40 halfs = 80B -> <=2-way bank aliasing (free)
  __shared__ __half Bs[64][40];
  const int dir = blockIdx.z / T_, t = blockIdx.z % T_;
  const int b0 = blockIdx.x*128, g0 = blockIdx.y*64;
  const int tid = threadIdx.x;
  const int wave = tid>>6, lane = tid&63;
  const int quad = lane>>4, lr = lane&15;
  f32x4_ acc[2][4];
#pragma unroll
  for (int i=0;i<2;i++)
#pragma unroll
    for (int j=0;j<4;j++) acc[i][j] = (f32x4_){0.f,0.f,0.f,0.f};

  const int sr  = tid>>2;        // staging row 0..63
  const int seg = (tid&3)*8;     // k-segment 0,8,16,24

  for (int k0=0;k0<Kpad;k0+=32){
    const int gk = k0 + seg;
    // A tile: 128 rows x 32 halfs, two passes of 64 rows
#pragma unroll
    for (int p=0;p<2;p++){
      int r = sr + 64*p;
      __half tmp[8];
      load8_(&inp[((size_t)(b0+r)*T_ + t)*Kmem + gk], Kmem - gk, tmp);
      *(uint4*)&As[r][seg] = *(uint4*)tmp;
    }
    // B tile: 64 rows x 32 halfs (fp32 weights converted inline)
    {
      __half tmp[8];
      load8_(&Wi[((size_t)dir*G_ + g0 + sr)*Kmem + gk], Kmem - gk, tmp);
      *(uint4*)&Bs[sr][seg] = *(uint4*)tmp;
    }
    __syncthreads();
    half8_ av[2], bv[4];
#pragma unroll
    for (int i=0;i<2;i++) av[i] = *(const half8_*)&As[wave*32 + i*16 + lr][quad*8];
#pragma unroll
    for (int j=0;j<4;j++) bv[j] = *(const half8_*)&Bs[j*16 + lr][quad*8];
#pragma unroll
    for (int i=0;i<2;i++)
#pragma unroll
      for (int j=0;j<4;j++)
        acc[i][j] = __builtin_amdgcn_mfma_f32_16x16x32_f16(av[i], bv[j], acc[i][j], 0, 0, 0);
    __syncthreads();
  }
  float bj[4];
#pragma unroll
  for (int j=0;j<4;j++) bj[j] = bihL[dir*G_ + g0 + j*16 + lr];
  const size_t obase = (size_t)(dir*T_ + t)*C*(size_t)G_;
#pragma unroll
  for (int i=0;i<2;i++){
#pragma unroll
    for (int r=0;r<4;r++){
      int row = b0 + wave*32 + i*16 + quad*4 + r;
#pragma unroll
      for (int j=0;j<4;j++){
        int col = g0 + j*16 + lr;
        gx[obase + (size_t)row*G_ + col] = __float2half(acc[i][j][r] + bj[j]);
      }
    }
  }
}

// ---------------- GRU recurrence: one block = 8 batch rows x 1 direction, all T steps.
// 8 rows/block -> 512 blocks = 2 blocks/CU = 8 waves/CU for latency hiding.
__global__ __launch_bounds__(256) void k_gru_rec(
    const __half* __restrict__ gx,    // [2][T][C][G] fp16 (this layer, this chunk)
    const __half* __restrict__ WTl,   // [2][H][G] fp16 (this layer, k-major)
    const float*  __restrict__ bhhL,  // [2][G] fp32
    __half* __restrict__ out,         // [C][T][DC] fp16; dir writes cols dir*H..dir*H+255
    float*  __restrict__ hsum,        // [2][C][H] fp32 running sum of h_finals
    int init, int C)
{
  int dir = blockIdx.y;
  int b0  = blockIdx.x * 8;
  int j   = threadIdx.x;           // 0..255 gate column
  __shared__ float hs[8][H_];
#pragma unroll
  for (int b=0;b<8;b++) hs[b][j] = 0.f;
  __syncthreads();
  const float bR = bhhL[dir*G_ + j];
  const float bZ = bhhL[dir*G_ + H_ + j];
  const float bN = bhhL[dir*G_ + 2*H_ + j];
  const __half* WTd = WTl + (size_t)dir*H_*G_;
  for (int t=0;t<T_;t++){
    int tt = dir ? (T_-1-t) : t;
    float aR[8], aZ[8], aN[8];
#pragma unroll
    for (int b=0;b<8;b++){ aR[b]=bR; aZ[b]=bZ; aN[b]=bN; }
    for (int k=0;k<H_;k+=4){
      float4 h4[8];
#pragma unroll
      for (int b=0;b<8;b++) h4[b] = *(const float4*)&hs[b][k];
#pragma unroll
      for (int kk=0;kk<4;kk++){
        const __half* wrow = WTd + (size_t)(k+kk)*G_;
        float w0 = __half2float(wrow[j]);
        float w1 = __half2float(wrow[H_ + j]);
        float w2 = __half2float(wrow[2*H_ + j]);
#pragma unroll
        for (int b=0;b<8;b++){
          float hv = ((const float*)&h4[b])[kk];
          aR[b] = fmaf(hv, w0, aR[b]);
          aZ[b] = fmaf(hv, w1, aZ[b]);
          aN[b] = fmaf(hv, w2, aN[b]);
        }
      }
    }
    __syncthreads();   // all hs reads for this step complete
    const __half* gxp = gx + ((size_t)(dir*T_ + tt)*C + b0)*G_;
#pragma unroll
    for (int b=0;b<8;b++){
      float gr = __half2float(gxp[(size_t)b*G_ + j]);
      float gz = __half2float(gxp[(size_t)b*G_ + H_  + j]);
      float gn = __half2float(gxp[(size_t)b*G_ + 2*H_ + j]);
      float r = sigmoidf_(gr + aR[b]);
      float z = sigmoidf_(gz + aZ[b]);
      float n = tanhf(gn + r*aN[b]);   // b_hn folded into aN -> multiplied by r (PyTorch semantics)
      float hnew = (1.f - z)*n + z*hs[b][j];
      out[((size_t)(b0+b)*T_ + tt)*DC_ + dir*H_ + j] = __float2half(hnew);
      hs[b][j] = hnew;
    }
    __syncthreads();   // hs update visible before next step's reads
  }
  if (init){
#pragma unroll
    for (int b=0;b<8;b++)
      hsum[((size_t)dir*C + b0 + b)*H_ + j] = hs[b][j];
  } else {
#pragma unroll
    for (int b=0;b<8;b++)
      hsum[((size_t)dir*C + b0 + b)*H_ + j] += hs[b][j];
  }
}

// ---------------- head (per chunk): mean of 16 h_finals -> 256->64 silu -> 64->32 silu -> 32->1
__global__ __launch_bounds__(256) void k_head(
    const float* __restrict__ hsum, // [2][C][H] (sum over 8 layers per dir)
    const float* __restrict__ W1, const float* __restrict__ b1,
    const float* __restrict__ W2, const float* __restrict__ b2,
    const float* __restrict__ Wc, const float* __restrict__ bc,
    float* __restrict__ outp, int C) // outp pre-offset to chunk base
{
  __shared__ float hb[4][H_];
  __shared__ float y1[4][64];
  __shared__ float y2[4][32];
  int w = threadIdx.x >> 6, lane = threadIdx.x & 63;
  int b = blockIdx.x*4 + w;
  for (int i=lane;i<H_;i+=64){
    float s = hsum[(size_t)b*H_ + i] + hsum[((size_t)C + b)*H_ + i];
    hb[w][i] = s * (1.f/16.f);
  }
  __syncthreads();
  {
    float s = b1[lane];
#pragma unroll 8
    for (int k=0;k<H_;k++) s = fmaf(W1[lane*H_ + k], hb[w][k], s);
    y1[w][lane] = s * (1.f/(1.f+expf(-s)));
  }
  __syncthreads();
  if (lane < 32){
    float s = b2[lane];
#pragma unroll
    for (int k=0;k<64;k++) s = fmaf(W2[lane*64 + k], y1[w][k], s);
    y2[w][lane] = s * (1.f/(1.f+expf(-s)));
  }
  __syncthreads();
  if (lane == 0){
    float s = bc[0];
#pragma unroll
    for (int k=0;k<32;k++) s = fmaf(Wc[k], y2[w][k], s);
    outp[b] = s;
  }
}

static inline size_t al256(size_t x){ return (x + 255) & ~(size_t)255; }

extern "C" void kernel_launch(void* const* d_in, const int* in_sizes, int n_in,
                              void* d_out, int out_size, void* d_ws, size_t ws_size,
                              hipStream_t stream)
{
  const float* x    = (const float*)d_in[0];
  const float* Wih0 = (const float*)d_in[1];
  const float* WihR = (const float*)d_in[2];
  const float* Whh  = (const float*)d_in[3];
  const float* bih  = (const float*)d_in[4];
  const float* bhh  = (const float*)d_in[5];
  const float* W1p  = (const float*)d_in[6];
  const float* b1p  = (const float*)d_in[7];
  const float* W2p  = (const float*)d_in[8];
  const float* b2p  = (const float*)d_in[9];
  const float* Wcp  = (const float*)d_in[10];
  const float* bcp  = (const float*)d_in[11];
  float* outp = (float*)d_out;
  (void)in_sizes; (void)n_in;

  // ---- pick smallest chunk count NC whose ws footprint fits ws_size (R4-proven layout) ----
  auto need = [](int nc) -> size_t {
    size_t c = B_ / nc;
    size_t s = 0;
    s += al256((size_t)2*T_*c*G_*sizeof(__half));   // gx
    s += al256((size_t)c*T_*DC_*sizeof(__half));    // buf
    s += al256((size_t)16*H_*G_*sizeof(__half));    // WT
    s += al256((size_t)2*c*H_*sizeof(float));       // hsum
    return s;
  };
  const int ncs[5] = {1,2,4,8,16};
  int NC = 16; bool fits = false;
  for (int i=0;i<5;i++){ if (need(ncs[i]) <= ws_size){ NC = ncs[i]; fits = true; break; } }

  if (!fits){
    k_zero<<<(out_size + 255)/256, 256, 0, stream>>>(outp, out_size);
    return;
  }

  const size_t C = B_ / NC;
  char* p = (char*)d_ws;
  __half* gx   = (__half*)p;  p += al256((size_t)2*T_*C*G_*sizeof(__half));
  __half* buf  = (__half*)p;  p += al256((size_t)C*T_*DC_*sizeof(__half));
  __half* WT   = (__half*)p;  p += al256((size_t)16*H_*G_*sizeof(__half));
  float*  hsum = (float*)p;   p += al256((size_t)2*C*H_*sizeof(float));

  k_transpose_whh<<<dim3(G_/32, H_/32, 16), 256, 0, stream>>>(Whh, WT);

  for (int cc=0; cc<NC; cc++){
    const size_t b0c = (size_t)cc * C;
    for (int l=0;l<L_;l++){
      const float* Wi = (l==0) ? Wih0 : (WihR + (size_t)(l-1)*2*G_*DC_);
      if (l==0){
        k_gx_mfma<float><<<dim3(C/128, G_/64, 2*T_), 256, 0, stream>>>(
            x + b0c*T_*D0_, Wi, bih + (size_t)l*2*G_, gx, (int)C, D0_, 192);
      } else {
        k_gx_mfma<__half><<<dim3(C/128, G_/64, 2*T_), 256, 0, stream>>>(
            buf, Wi, bih + (size_t)l*2*G_, gx, (int)C, DC_, DC_);
      }
      // both GEMM dispatches above finish reading `buf` before rec overwrites it (stream order)
      k_gru_rec<<<dim3(C/8, 2), 256, 0, stream>>>(
          gx, WT + (size_t)l*2*H_*G_, bhh + (size_t)l*2*G_, buf,
          hsum, (l==0) ? 1 : 0, (int)C);
    }
    k_head<<<dim3(C/4), 256, 0, stream>>>(hsum, W1p,b1p,W2p,b2p,Wcp,bcp,
                                          outp + b0c, (int)C);
  }
}

// Round 7
// 2173.113 us; speedup vs baseline: 5.9154x; 1.7951x over previous
//
#include <hip/hip_runtime.h>
#include <hip/hip_fp16.h>
#include <cstdint>
#include <cstddef>

#define B_   2048
#define T_   13
#define D0_  188
#define H_   256
#define G_   768   // 3*H
#define L_   8
#define DC_  512   // 2*H concat width
#define WFLD_ (8*48*64*8)   // halfs per (layer,dir) in fragment-packed W_hh = 196608

typedef _Float16 half8_ __attribute__((ext_vector_type(8)));
typedef float    f32x4_ __attribute__((ext_vector_type(4)));

__device__ __forceinline__ float sigmoidf_(float x){ return 1.f/(1.f + expf(-x)); }

// ---------------- fallback: zero d_out (diagnostic path if ws_size is tiny) ----------------
__global__ __launch_bounds__(256) void k_zero(float* __restrict__ o, int n){
  int i = blockIdx.x*256 + threadIdx.x;
  if (i < n) o[i] = 0.f;
}

// ---------------- pack W_hh [16][G][H] fp32 -> MFMA B-fragment layout fp16:
// WF[ld][kk(8)][c(48)][lane(64)][8], frag elem j: B[n=lane&15][k=(lane>>4)*8+j] of tile (c,kk)
// i.e. WF[...] = W[ld][c*16+(lane&15)][kk*32+(lane>>4)*8+j]
__global__ __launch_bounds__(64) void k_pack_whh(const float* __restrict__ W,
                                                 __half* __restrict__ WF){
  int kk = blockIdx.x, c = blockIdx.y, ld = blockIdx.z;
  int lane = threadIdx.x, n = lane & 15, quad = lane >> 4;
  int col = c*16 + n;
  const float* src = W + ((size_t)ld*G_ + col)*H_ + kk*32 + quad*8;
  __half tmp[8];
#pragma unroll
  for (int j=0;j<8;j++) tmp[j] = __float2half(src[j]);
  *(uint4*)(WF + (size_t)ld*WFLD_ + (((size_t)kk*48 + c)*64 + lane)*8) = *(uint4*)tmp;
}

// ---------------- staging helpers: load 8 elems (guarded) -> 8 halfs ----------------
__device__ __forceinline__ void load8_(const float* s, int rem, __half* d){
  if (rem >= 8){
#pragma unroll
    for (int u=0;u<8;u++) d[u] = __float2half(s[u]);
  } else {
#pragma unroll
    for (int u=0;u<8;u++) d[u] = (u<rem) ? __float2half(s[u]) : __ushort_as_half((unsigned short)0);
  }
}
__device__ __forceinline__ void load8_(const __half* s, int rem, __half* d){
  if (rem >= 8){
    *(uint4*)d = *(const uint4*)s;      // 16B vector load (layers>=1: always aligned, K%8==0)
  } else {
#pragma unroll
    for (int u=0;u<8;u++) d[u] = (u<rem) ? s[u] : __ushort_as_half((unsigned short)0);
  }
}

// ---------------- gx GEMM via MFMA f16 (R6-proven):
// gx[dir][t][b][g] = b_ih[dir][g] + sum_k inp[b][t][k] * Wi[dir][g][k]
template<typename TIN>
__global__ __launch_bounds__(256) void k_gx_mfma(
    const TIN* __restrict__ inp,     // [C][T][Kmem]  (fp32 for layer 0, fp16 after)
    const float* __restrict__ Wi,    // [2][G][Kmem] fp32
    const float* __restrict__ bihL,  // [2][G] fp32
    __half* __restrict__ gx,         // [2][T][C][G] fp16
    int C, int Kmem, int Kpad)
{
  __shared__ __half As[128][40];
  __shared__ __half Bs[64][40];
  const int dir = blockIdx.z / T_, t = blockIdx.z % T_;
  const int b0 = blockIdx.x*128, g0 = blockIdx.y*64;
  const int tid = threadIdx.x;
  const int wave = tid>>6, lane = tid&63;
  const int quad = lane>>4, lr = lane&15;
  f32x4_ acc[2][4];
#pragma unroll
  for (int i=0;i<2;i++)
#pragma unroll
    for (int j=0;j<4;j++) acc[i][j] = (f32x4_){0.f,0.f,0.f,0.f};

  const int sr  = tid>>2;
  const int seg = (tid&3)*8;

  for (int k0=0;k0<Kpad;k0+=32){
    const int gk = k0 + seg;
#pragma unroll
    for (int p=0;p<2;p++){
      int r = sr + 64*p;
      __half tmp[8];
      load8_(&inp[((size_t)(b0+r)*T_ + t)*Kmem + gk], Kmem - gk, tmp);
      *(uint4*)&As[r][seg] = *(uint4*)tmp;
    }
    {
      __half tmp[8];
      load8_(&Wi[((size_t)dir*G_ + g0 + sr)*Kmem + gk], Kmem - gk, tmp);
      *(uint4*)&Bs[sr][seg] = *(uint4*)tmp;
    }
    __syncthreads();
    half8_ av[2], bv[4];
#pragma unroll
    for (int i=0;i<2;i++) av[i] = *(const half8_*)&As[wave*32 + i*16 + lr][quad*8];
#pragma unroll
    for (int j=0;j<4;j++) bv[j] = *(const half8_*)&Bs[j*16 + lr][quad*8];
#pragma unroll
    for (int i=0;i<2;i++)
#pragma unroll
      for (int j=0;j<4;j++)
        acc[i][j] = __builtin_amdgcn_mfma_f32_16x16x32_f16(av[i], bv[j], acc[i][j], 0, 0, 0);
    __syncthreads();
  }
  float bj[4];
#pragma unroll
  for (int j=0;j<4;j++) bj[j] = bihL[dir*G_ + g0 + j*16 + lr];
  const size_t obase = (size_t)(dir*T_ + t)*C*(size_t)G_;
#pragma unroll
  for (int i=0;i<2;i++){
#pragma unroll
    for (int r=0;r<4;r++){
      int row = b0 + wave*32 + i*16 + quad*4 + r;
#pragma unroll
      for (int j=0;j<4;j++){
        int col = g0 + j*16 + lr;
        gx[obase + (size_t)row*G_ + col] = __float2half(acc[i][j][r] + bj[j]);
      }
    }
  }
}

// ---------------- GRU recurrence via MFMA: one block = 16 batch rows x 1 dir, all T steps.
// 256 blocks = 1/CU. Per step: gh[16][768] = h_f16[16][256] @ W^T via 96 mfma/wave.
// Wave w owns ntiles c == w (mod 4): triples (c, c+16, c+32) stay in-wave -> gate math on
// accumulators in registers; h_old in registers; LDS only holds h as f16 A-source.
__global__ __launch_bounds__(256) void k_gru_rec(
    const __half* __restrict__ gx,    // [2][T][C][G] fp16 (this layer, this chunk)
    const __half* __restrict__ WFl,   // [2][8][48][64][8] fp16 (this layer, frag-packed)
    const float*  __restrict__ bhhL,  // [2][G] fp32
    __half* __restrict__ out,         // [C][T][DC] fp16; dir writes cols dir*H..dir*H+255
    float*  __restrict__ hsum,        // [2][C][H] fp32 running sum of h_finals
    int init, int C)
{
  const int dir  = blockIdx.y;
  const int b0   = blockIdx.x * 16;
  const int tid  = threadIdx.x;
  const int wave = tid >> 6, lane = tid & 63;
  const int quad = lane >> 4, ln = lane & 15;

  __shared__ __half hsA[16][264];    // [batch row][hidden k], pad 8 -> balanced banks
  for (int i = tid; i < 16*264; i += 256) ((__half*)hsA)[i] = __ushort_as_half((unsigned short)0);

  // this lane's 16 owned units: rows quad*4+r, cols (wave+4i)*16+ln, i=0..3
  float hreg[4][4];
#pragma unroll
  for (int i=0;i<4;i++)
#pragma unroll
    for (int r=0;r<4;r++) hreg[i][r] = 0.f;

  float bR[4], bZ[4], bN[4];
#pragma unroll
  for (int i=0;i<4;i++){
    int col = (wave + 4*i)*16 + ln;
    bR[i] = bhhL[dir*G_ + col];
    bZ[i] = bhhL[dir*G_ + H_  + col];
    bN[i] = bhhL[dir*G_ + 2*H_ + col];
  }

  const half8_* WF8 = (const half8_*)(WFl + (size_t)dir*WFLD_);  // [kk][c][lane] half8
  __syncthreads();

  for (int t=0;t<T_;t++){
    const int tt = dir ? (T_-1-t) : t;

    // ---- MFMA phase: acc[m] = tile (Mtile0, ntile c=wave+4m), m=0..11 ----
    f32x4_ acc[12];
#pragma unroll
    for (int m=0;m<12;m++) acc[m] = (f32x4_){0.f,0.f,0.f,0.f};

    half8_ bf[2][12];
#pragma unroll
    for (int m=0;m<12;m++) bf[0][m] = WF8[(size_t)(0*48 + wave + 4*m)*64 + lane];
#pragma unroll
    for (int kk=0;kk<8;kk++){
      const int cur = kk & 1, nxt = cur ^ 1;
      if (kk < 7){
#pragma unroll
        for (int m=0;m<12;m++) bf[nxt][m] = WF8[(size_t)((kk+1)*48 + wave + 4*m)*64 + lane];
      }
      half8_ af = *(const half8_*)&hsA[ln][kk*32 + quad*8];
#pragma unroll
      for (int m=0;m<12;m++)
        acc[m] = __builtin_amdgcn_mfma_f32_16x16x32_f16(af, bf[cur][m], acc[m], 0, 0, 0);
    }

    // ---- gate phase (no hsA access; h_old in regs) ----
    const __half* gxp = gx + ((size_t)(dir*T_ + tt)*C + b0)*G_;
    float hnew[4][4];
#pragma unroll
    for (int i=0;i<4;i++){
      const int col = (wave + 4*i)*16 + ln;
#pragma unroll
      for (int r=0;r<4;r++){
        const int row = quad*4 + r;
        float gr = __half2float(gxp[(size_t)row*G_ + col]);
        float gz = __half2float(gxp[(size_t)row*G_ + H_  + col]);
        float gn = __half2float(gxp[(size_t)row*G_ + 2*H_ + col]);
        float rr = sigmoidf_(gr + bR[i] + acc[i  ][r]);
        float zz = sigmoidf_(gz + bZ[i] + acc[i+4][r]);
        float nn = tanhf(gn + rr*(bN[i] + acc[i+8][r]));   // b_hn inside r* (PyTorch semantics)
        hnew[i][r] = (1.f - zz)*nn + zz*hreg[i][r];
        hreg[i][r] = hnew[i][r];
      }
    }
    __syncthreads();   // all waves' A-frag reads of old h complete
#pragma unroll
    for (int i=0;i<4;i++){
      const int col = (wave + 4*i)*16 + ln;
#pragma unroll
      for (int r=0;r<4;r++){
        const int row = quad*4 + r;
        __half hv = __float2half(hnew[i][r]);
        hsA[row][col] = hv;
        out[((size_t)(b0+row)*T_ + tt)*DC_ + dir*H_ + col] = hv;
      }
    }
    __syncthreads();   // new h visible before next step's A-frag reads
  }

#pragma unroll
  for (int i=0;i<4;i++){
    const int col = (wave + 4*i)*16 + ln;
#pragma unroll
    for (int r=0;r<4;r++){
      const int row = quad*4 + r;
      float* dst = &hsum[((size_t)dir*C + b0 + row)*H_ + col];
      if (init) *dst = hreg[i][r]; else *dst += hreg[i][r];
    }
  }
}

// ---------------- head (per chunk): mean of 16 h_finals -> 256->64 silu -> 64->32 silu -> 32->1
__global__ __launch_bounds__(256) void k_head(
    const float* __restrict__ hsum, // [2][C][H] (sum over 8 layers per dir)
    const float* __restrict__ W1, const float* __restrict__ b1,
    const float* __restrict__ W2, const float* __restrict__ b2,
    const float* __restrict__ Wc, const float* __restrict__ bc,
    float* __restrict__ outp, int C) // outp pre-offset to chunk base
{
  __shared__ float hb[4][H_];
  __shared__ float y1[4][64];
  __shared__ float y2[4][32];
  int w = threadIdx.x >> 6, lane = threadIdx.x & 63;
  int b = blockIdx.x*4 + w;
  for (int i=lane;i<H_;i+=64){
    float s = hsum[(size_t)b*H_ + i] + hsum[((size_t)C + b)*H_ + i];
    hb[w][i] = s * (1.f/16.f);
  }
  __syncthreads();
  {
    float s = b1[lane];
#pragma unroll 8
    for (int k=0;k<H_;k++) s = fmaf(W1[lane*H_ + k], hb[w][k], s);
    y1[w][lane] = s * (1.f/(1.f+expf(-s)));
  }
  __syncthreads();
  if (lane < 32){
    float s = b2[lane];
#pragma unroll
    for (int k=0;k<64;k++) s = fmaf(W2[lane*64 + k], y1[w][k], s);
    y2[w][lane] = s * (1.f/(1.f+expf(-s)));
  }
  __syncthreads();
  if (lane == 0){
    float s = bc[0];
#pragma unroll
    for (int k=0;k<32;k++) s = fmaf(Wc[k], y2[w][k], s);
    outp[b] = s;
  }
}

static inline size_t al256(size_t x){ return (x + 255) & ~(size_t)255; }

extern "C" void kernel_launch(void* const* d_in, const int* in_sizes, int n_in,
                              void* d_out, int out_size, void* d_ws, size_t ws_size,
                              hipStream_t stream)
{
  const float* x    = (const float*)d_in[0];
  const float* Wih0 = (const float*)d_in[1];
  const float* WihR = (const float*)d_in[2];
  const float* Whh  = (const float*)d_in[3];
  const float* bih  = (const float*)d_in[4];
  const float* bhh  = (const float*)d_in[5];
  const float* W1p  = (const float*)d_in[6];
  const float* b1p  = (const float*)d_in[7];
  const float* W2p  = (const float*)d_in[8];
  const float* b2p  = (const float*)d_in[9];
  const float* Wcp  = (const float*)d_in[10];
  const float* bcp  = (const float*)d_in[11];
  float* outp = (float*)d_out;
  (void)in_sizes; (void)n_in;

  // ---- pick smallest chunk count NC whose ws footprint fits ws_size (R4-proven layout) ----
  // NOTE: WF slot (frag-packed W_hh) is byte-identical to the old WT slot: 16*H*G halfs.
  auto need = [](int nc) -> size_t {
    size_t c = B_ / nc;
    size_t s = 0;
    s += al256((size_t)2*T_*c*G_*sizeof(__half));   // gx
    s += al256((size_t)c*T_*DC_*sizeof(__half));    // buf
    s += al256((size_t)16*H_*G_*sizeof(__half));    // WF (== 16*WFLD_ halfs)
    s += al256((size_t)2*c*H_*sizeof(float));       // hsum
    return s;
  };
  const int ncs[5] = {1,2,4,8,16};
  int NC = 16; bool fits = false;
  for (int i=0;i<5;i++){ if (need(ncs[i]) <= ws_size){ NC = ncs[i]; fits = true; break; } }

  if (!fits){
    k_zero<<<(out_size + 255)/256, 256, 0, stream>>>(outp, out_size);
    return;
  }

  const size_t C = B_ / NC;
  char* p = (char*)d_ws;
  __half* gx   = (__half*)p;  p += al256((size_t)2*T_*C*G_*sizeof(__half));
  __half* buf  = (__half*)p;  p += al256((size_t)C*T_*DC_*sizeof(__half));
  __half* WF   = (__half*)p;  p += al256((size_t)16*H_*G_*sizeof(__half));
  float*  hsum = (float*)p;   p += al256((size_t)2*C*H_*sizeof(float));

  k_pack_whh<<<dim3(8, 48, 16), 64, 0, stream>>>(Whh, WF);

  for (int cc=0; cc<NC; cc++){
    const size_t b0c = (size_t)cc * C;
    for (int l=0;l<L_;l++){
      const float* Wi = (l==0) ? Wih0 : (WihR + (size_t)(l-1)*2*G_*DC_);
      if (l==0){
        k_gx_mfma<float><<<dim3(C/128, G_/64, 2*T_), 256, 0, stream>>>(
            x + b0c*T_*D0_, Wi, bih + (size_t)l*2*G_, gx, (int)C, D0_, 192);
      } else {
        k_gx_mfma<__half><<<dim3(C/128, G_/64, 2*T_), 256, 0, stream>>>(
            buf, Wi, bih + (size_t)l*2*G_, gx, (int)C, DC_, DC_);
      }
      // GEMM dispatches finish reading `buf` before rec overwrites it (stream order)
      k_gru_rec<<<dim3(C/16, 2), 256, 0, stream>>>(
          gx, WF + (size_t)l*2*WFLD_, bhh + (size_t)l*2*G_, buf,
          hsum, (l==0) ? 1 : 0, (int)C);
    }
    k_head<<<dim3(C/4), 256, 0, stream>>>(hsum, W1p,b1p,W2p,b2p,Wcp,bcp,
                                          outp + b0c, (int)C);
  }
}

// Round 8
// 1753.542 us; speedup vs baseline: 7.3308x; 1.2393x over previous
//
#include <hip/hip_runtime.h>
#include <hip/hip_fp16.h>
#include <cstdint>
#include <cstddef>

#define B_   2048
#define T_   13
#define D0_  188
#define H_   256
#define G_   768   // 3*H
#define L_   8
#define DC_  512   // 2*H concat width
#define WFLD_ (8*48*64*8)   // halfs per (layer,dir) in fragment-packed W_hh = 196608

typedef _Float16 half8_ __attribute__((ext_vector_type(8)));
typedef float    f32x4_ __attribute__((ext_vector_type(4)));

__device__ __forceinline__ float sigmoidf_(float x){ return 1.f/(1.f + expf(-x)); }

// ---------------- fallback: zero d_out (diagnostic path if ws_size is tiny) ----------------
__global__ __launch_bounds__(256) void k_zero(float* __restrict__ o, int n){
  int i = blockIdx.x*256 + threadIdx.x;
  if (i < n) o[i] = 0.f;
}

// ---------------- pack W_hh [16][G][H] fp32 -> MFMA B-fragment layout fp16:
// WF[ld][kk(8)][c(48)][lane(64)][8], frag elem j: B[n=lane&15][k=(lane>>4)*8+j] of tile (c,kk)
__global__ __launch_bounds__(64) void k_pack_whh(const float* __restrict__ W,
                                                 __half* __restrict__ WF){
  int kk = blockIdx.x, c = blockIdx.y, ld = blockIdx.z;
  int lane = threadIdx.x, n = lane & 15, quad = lane >> 4;
  int col = c*16 + n;
  const float* src = W + ((size_t)ld*G_ + col)*H_ + kk*32 + quad*8;
  __half tmp[8];
#pragma unroll
  for (int j=0;j<8;j++) tmp[j] = __float2half(src[j]);
  *(uint4*)(WF + (size_t)ld*WFLD_ + (((size_t)kk*48 + c)*64 + lane)*8) = *(uint4*)tmp;
}

// ---------------- staging helpers: load 8 elems (guarded) -> 8 halfs ----------------
__device__ __forceinline__ void load8_(const float* s, int rem, __half* d){
  if (rem >= 8){
#pragma unroll
    for (int u=0;u<8;u++) d[u] = __float2half(s[u]);
  } else {
#pragma unroll
    for (int u=0;u<8;u++) d[u] = (u<rem) ? __float2half(s[u]) : __ushort_as_half((unsigned short)0);
  }
}
__device__ __forceinline__ void load8_(const __half* s, int rem, __half* d){
  if (rem >= 8){
    *(uint4*)d = *(const uint4*)s;
  } else {
#pragma unroll
    for (int u=0;u<8;u++) d[u] = (u<rem) ? s[u] : __ushort_as_half((unsigned short)0);
  }
}

// ---------------- gx GEMM via MFMA f16 (R6-proven) ----------------
template<typename TIN>
__global__ __launch_bounds__(256) void k_gx_mfma(
    const TIN* __restrict__ inp,     // [C][T][Kmem]
    const float* __restrict__ Wi,    // [2][G][Kmem] fp32
    const float* __restrict__ bihL,  // [2][G] fp32
    __half* __restrict__ gx,         // [2][T][C][G] fp16
    int C, int Kmem, int Kpad)
{
  __shared__ __half As[128][40];
  __shared__ __half Bs[64][40];
  const int dir = blockIdx.z / T_, t = blockIdx.z % T_;
  const int b0 = blockIdx.x*128, g0 = blockIdx.y*64;
  const int tid = threadIdx.x;
  const int wave = tid>>6, lane = tid&63;
  const int quad = lane>>4, lr = lane&15;
  f32x4_ acc[2][4];
#pragma unroll
  for (int i=0;i<2;i++)
#pragma unroll
    for (int j=0;j<4;j++) acc[i][j] = (f32x4_){0.f,0.f,0.f,0.f};

  const int sr  = tid>>2;
  const int seg = (tid&3)*8;

  for (int k0=0;k0<Kpad;k0+=32){
    const int gk = k0 + seg;
#pragma unroll
    for (int p=0;p<2;p++){
      int r = sr + 64*p;
      __half tmp[8];
      load8_(&inp[((size_t)(b0+r)*T_ + t)*Kmem + gk], Kmem - gk, tmp);
      *(uint4*)&As[r][seg] = *(uint4*)tmp;
    }
    {
      __half tmp[8];
      load8_(&Wi[((size_t)dir*G_ + g0 + sr)*Kmem + gk], Kmem - gk, tmp);
      *(uint4*)&Bs[sr][seg] = *(uint4*)tmp;
    }
    __syncthreads();
    half8_ av[2], bv[4];
#pragma unroll
    for (int i=0;i<2;i++) av[i] = *(const half8_*)&As[wave*32 + i*16 + lr][quad*8];
#pragma unroll
    for (int j=0;j<4;j++) bv[j] = *(const half8_*)&Bs[j*16 + lr][quad*8];
#pragma unroll
    for (int i=0;i<2;i++)
#pragma unroll
      for (int j=0;j<4;j++)
        acc[i][j] = __builtin_amdgcn_mfma_f32_16x16x32_f16(av[i], bv[j], acc[i][j], 0, 0, 0);
    __syncthreads();
  }
  float bj[4];
#pragma unroll
  for (int j=0;j<4;j++) bj[j] = bihL[dir*G_ + g0 + j*16 + lr];
  const size_t obase = (size_t)(dir*T_ + t)*C*(size_t)G_;
#pragma unroll
  for (int i=0;i<2;i++){
#pragma unroll
    for (int r=0;r<4;r++){
      int row = b0 + wave*32 + i*16 + quad*4 + r;
#pragma unroll
      for (int j=0;j<4;j++){
        int col = g0 + j*16 + lr;
        gx[obase + (size_t)row*G_ + col] = __float2half(acc[i][j][r] + bj[j]);
      }
    }
  }
}

// ---------------- GRU recurrence via MFMA, latency-hidden step loop.
// One block = 16 batch rows x 1 dir; per step: issue Wstage0 loads -> deferred out-stores
// (prev step's h) -> gx prefetch loads -> 8 dbuf MFMA stages (loads retire under them)
// -> gate math from registers -> barrier -> LDS h update -> barrier.
__global__ __launch_bounds__(256) void k_gru_rec(
    const __half* __restrict__ gx,    // [2][T][C][G] fp16
    const __half* __restrict__ WFl,   // [2][8][48][64][8] fp16 (frag-packed)
    const float*  __restrict__ bhhL,  // [2][G] fp32
    __half* __restrict__ out,         // [C][T][DC] fp16; dir writes cols dir*H..dir*H+255
    float*  __restrict__ hsum,        // [2][C][H] fp32
    int init, int C)
{
  const int dir  = blockIdx.y;
  const int b0   = blockIdx.x * 16;
  const int tid  = threadIdx.x;
  const int wave = tid >> 6, lane = tid & 63;
  const int quad = lane >> 4, ln = lane & 15;

  __shared__ __half hsA[16][264];
  for (int i = tid; i < 16*264; i += 256) ((__half*)hsA)[i] = __ushort_as_half((unsigned short)0);

  float hreg[4][4];
#pragma unroll
  for (int i=0;i<4;i++)
#pragma unroll
    for (int r=0;r<4;r++) hreg[i][r] = 0.f;

  float bR[4], bZ[4], bN[4];
#pragma unroll
  for (int i=0;i<4;i++){
    int col = (wave + 4*i)*16 + ln;
    bR[i] = bhhL[dir*G_ + col];
    bZ[i] = bhhL[dir*G_ + H_  + col];
    bN[i] = bhhL[dir*G_ + 2*H_ + col];
  }

  const half8_* WF8 = (const half8_*)(WFl + (size_t)dir*WFLD_);
  __syncthreads();

  int ttprev = 0;
  for (int t=0;t<T_;t++){
    const int tt = dir ? (T_-1-t) : t;

    // ---- (1) weight stage-0 prefetch (oldest vmcnt entries: MFMA wait won't drain stores/gx)
    half8_ bf[2][12];
#pragma unroll
    for (int m=0;m<12;m++) bf[0][m] = WF8[(size_t)(0*48 + wave + 4*m)*64 + lane];

    // ---- (2) deferred out-store of previous step's h (retires under the MFMA phase)
    if (t > 0){
#pragma unroll
      for (int i=0;i<4;i++){
        const int col = (wave + 4*i)*16 + ln;
#pragma unroll
        for (int r=0;r<4;r++){
          const int row = quad*4 + r;
          out[((size_t)(b0+row)*T_ + ttprev)*DC_ + dir*H_ + col] = __float2half(hreg[i][r]);
        }
      }
    }

    // ---- (3) gx prefetch for this step (h-independent; hidden behind MFMA stages)
    const __half* gxp = gx + ((size_t)(dir*T_ + tt)*C + b0)*G_;
    __half gxh[3][4][4];
#pragma unroll
    for (int i=0;i<4;i++){
      const int col = (wave + 4*i)*16 + ln;
#pragma unroll
      for (int r=0;r<4;r++){
        const __half* pb = gxp + (size_t)(quad*4+r)*G_ + col;
        gxh[0][i][r] = pb[0];
        gxh[1][i][r] = pb[H_];
        gxh[2][i][r] = pb[2*H_];
      }
    }

    // ---- (4) MFMA phase: acc[m] = h @ W^T tile (ntile c = wave+4m), dbuf over kk ----
    f32x4_ acc[12];
#pragma unroll
    for (int m=0;m<12;m++) acc[m] = (f32x4_){0.f,0.f,0.f,0.f};
#pragma unroll
    for (int kk=0;kk<8;kk++){
      const int cur = kk & 1, nxt = cur ^ 1;
      if (kk < 7){
#pragma unroll
        for (int m=0;m<12;m++) bf[nxt][m] = WF8[(size_t)((kk+1)*48 + wave + 4*m)*64 + lane];
      }
      half8_ af = *(const half8_*)&hsA[ln][kk*32 + quad*8];
#pragma unroll
      for (int m=0;m<12;m++)
        acc[m] = __builtin_amdgcn_mfma_f32_16x16x32_f16(af, bf[cur][m], acc[m], 0, 0, 0);
    }

    // ---- (5) gate phase: everything in registers ----
#pragma unroll
    for (int i=0;i<4;i++){
#pragma unroll
      for (int r=0;r<4;r++){
        float gr = __half2float(gxh[0][i][r]);
        float gz = __half2float(gxh[1][i][r]);
        float gn = __half2float(gxh[2][i][r]);
        float rr = sigmoidf_(gr + bR[i] + acc[i  ][r]);
        float zz = sigmoidf_(gz + bZ[i] + acc[i+4][r]);
        float nn = tanhf(gn + rr*(bN[i] + acc[i+8][r]));   // b_hn inside r* (PyTorch semantics)
        hreg[i][r] = (1.f - zz)*nn + zz*hreg[i][r];
      }
    }
    __syncthreads();   // all waves' A-frag reads of old h complete
#pragma unroll
    for (int i=0;i<4;i++){
      const int col = (wave + 4*i)*16 + ln;
#pragma unroll
      for (int r=0;r<4;r++)
        hsA[quad*4 + r][col] = __float2half(hreg[i][r]);
    }
    __syncthreads();   // new h visible before next step's A-frag reads
    ttprev = tt;
  }

  // ---- final step's out-store + hsum ----
#pragma unroll
  for (int i=0;i<4;i++){
    const int col = (wave + 4*i)*16 + ln;
#pragma unroll
    for (int r=0;r<4;r++){
      const int row = quad*4 + r;
      out[((size_t)(b0+row)*T_ + ttprev)*DC_ + dir*H_ + col] = __float2half(hreg[i][r]);
      float* dst = &hsum[((size_t)dir*C + b0 + row)*H_ + col];
      if (init) *dst = hreg[i][r]; else *dst += hreg[i][r];
    }
  }
}

// ---------------- head (per chunk) ----------------
__global__ __launch_bounds__(256) void k_head(
    const float* __restrict__ hsum, // [2][C][H]
    const float* __restrict__ W1, const float* __restrict__ b1,
    const float* __restrict__ W2, const float* __restrict__ b2,
    const float* __restrict__ Wc, const float* __restrict__ bc,
    float* __restrict__ outp, int C)
{
  __shared__ float hb[4][H_];
  __shared__ float y1[4][64];
  __shared__ float y2[4][32];
  int w = threadIdx.x >> 6, lane = threadIdx.x & 63;
  int b = blockIdx.x*4 + w;
  for (int i=lane;i<H_;i+=64){
    float s = hsum[(size_t)b*H_ + i] + hsum[((size_t)C + b)*H_ + i];
    hb[w][i] = s * (1.f/16.f);
  }
  __syncthreads();
  {
    float s = b1[lane];
#pragma unroll 8
    for (int k=0;k<H_;k++) s = fmaf(W1[lane*H_ + k], hb[w][k], s);
    y1[w][lane] = s * (1.f/(1.f+expf(-s)));
  }
  __syncthreads();
  if (lane < 32){
    float s = b2[lane];
#pragma unroll
    for (int k=0;k<64;k++) s = fmaf(W2[lane*64 + k], y1[w][k], s);
    y2[w][lane] = s * (1.f/(1.f+expf(-s)));
  }
  __syncthreads();
  if (lane == 0){
    float s = bc[0];
#pragma unroll
    for (int k=0;k<32;k++) s = fmaf(Wc[k], y2[w][k], s);
    outp[b] = s;
  }
}

static inline size_t al256(size_t x){ return (x + 255) & ~(size_t)255; }

extern "C" void kernel_launch(void* const* d_in, const int* in_sizes, int n_in,
                              void* d_out, int out_size, void* d_ws, size_t ws_size,
                              hipStream_t stream)
{
  const float* x    = (const float*)d_in[0];
  const float* Wih0 = (const float*)d_in[1];
  const float* WihR = (const float*)d_in[2];
  const float* Whh  = (const float*)d_in[3];
  const float* bih  = (const float*)d_in[4];
  const float* bhh  = (const float*)d_in[5];
  const float* W1p  = (const float*)d_in[6];
  const float* b1p  = (const float*)d_in[7];
  const float* W2p  = (const float*)d_in[8];
  const float* b2p  = (const float*)d_in[9];
  const float* Wcp  = (const float*)d_in[10];
  const float* bcp  = (const float*)d_in[11];
  float* outp = (float*)d_out;
  (void)in_sizes; (void)n_in;

  auto need = [](int nc) -> size_t {
    size_t c = B_ / nc;
    size_t s = 0;
    s += al256((size_t)2*T_*c*G_*sizeof(__half));   // gx
    s += al256((size_t)c*T_*DC_*sizeof(__half));    // buf
    s += al256((size_t)16*H_*G_*sizeof(__half));    // WF
    s += al256((size_t)2*c*H_*sizeof(float));       // hsum
    return s;
  };
  const int ncs[5] = {1,2,4,8,16};
  int NC = 16; bool fits = false;
  for (int i=0;i<5;i++){ if (need(ncs[i]) <= ws_size){ NC = ncs[i]; fits = true; break; } }

  if (!fits){
    k_zero<<<(out_size + 255)/256, 256, 0, stream>>>(outp, out_size);
    return;
  }

  const size_t C = B_ / NC;
  char* p = (char*)d_ws;
  __half* gx   = (__half*)p;  p += al256((size_t)2*T_*C*G_*sizeof(__half));
  __half* buf  = (__half*)p;  p += al256((size_t)C*T_*DC_*sizeof(__half));
  __half* WF   = (__half*)p;  p += al256((size_t)16*H_*G_*sizeof(__half));
  float*  hsum = (float*)p;   p += al256((size_t)2*C*H_*sizeof(float));

  k_pack_whh<<<dim3(8, 48, 16), 64, 0, stream>>>(Whh, WF);

  for (int cc=0; cc<NC; cc++){
    const size_t b0c = (size_t)cc * C;
    for (int l=0;l<L_;l++){
      const float* Wi = (l==0) ? Wih0 : (WihR + (size_t)(l-1)*2*G_*DC_);
      if (l==0){
        k_gx_mfma<float><<<dim3(C/128, G_/64, 2*T_), 256, 0, stream>>>(
            x + b0c*T_*D0_, Wi, bih + (size_t)l*2*G_, gx, (int)C, D0_, 192);
      } else {
        k_gx_mfma<__half><<<dim3(C/128, G_/64, 2*T_), 256, 0, stream>>>(
            buf, Wi, bih + (size_t)l*2*G_, gx, (int)C, DC_, DC_);
      }
      k_gru_rec<<<dim3(C/16, 2), 256, 0, stream>>>(
          gx, WF + (size_t)l*2*WFLD_, bhh + (size_t)l*2*G_, buf,
          hsum, (l==0) ? 1 : 0, (int)C);
    }
    k_head<<<dim3(C/4), 256, 0, stream>>>(hsum, W1p,b1p,W2p,b2p,Wcp,bcp,
                                          outp + b0c, (int)C);
  }
}